// Round 4
// baseline (76.504 us; speedup 1.0000x reference)
//
#include <hip/hip_runtime.h>

// TransformLayer: per-pixel reprojection, B=8 H=768 W=1024, fp32.
// Memory-bound: 25.2 MB read + 100.7 MB write -> ~19 us mixed-stream floor.
// R1: raw v_rcp/v_sqrt + FMA contraction (33->25.2 us).
// R2: 8 px/thread (2x4 groups), nontemporal stores, fma-folded index math.
// R3: fix - __builtin_nontemporal_store needs clang ext_vector_type, not HIP float4.

#define EPSF 1e-06f

typedef float f32x4 __attribute__((ext_vector_type(4)));

constexpr int Bc = 8;
constexpr int Hc = 768;
constexpr int Wc = 1024;
constexpr int HW = Hc * Wc;          // 786432
constexpr int THREADS = 256;
constexpr int PIX_PER_THREAD = 8;    // 2 x float4 groups
constexpr int BLOCKS_X = HW / (THREADS * PIX_PER_THREAD); // 384

__device__ __forceinline__ float frcp(float x)   { return __builtin_amdgcn_rcpf(x); }
__device__ __forceinline__ float fsqrtf_(float x){ return __builtin_amdgcn_sqrtf(x); }

__global__ __launch_bounds__(THREADS)
void transform_layer_kernel(const float* __restrict__ inv_depth,
                            const float* __restrict__ transform,
                            const float* __restrict__ calib_i,
                            const float* __restrict__ lam_i_p,
                            const float* __restrict__ calib_j,
                            const float* __restrict__ lam_j_p,
                            float* __restrict__ out)
{
    const int b    = blockIdx.y;                          // batch (wave-uniform)
    const int g8   = blockIdx.x * THREADS + threadIdx.x;  // 8-pixel group index
    const int p0   = g8 * PIX_PER_THREAD;                 // first pixel in group
    const int yrow = p0 >> 10;                            // p0 / W
    const int x0   = p0 & (Wc - 1);                       // p0 % W (same row, W%8==0)

    // Per-batch params (uniform addresses -> scalar loads)
    const float* T = transform + b * 16;
    const float t00=T[0], t01=T[1], t02=T[2], t03=T[3];
    const float t10=T[4], t11=T[5], t12=T[6], t13=T[7];
    const float t20=T[8], t21=T[9], t22=T[10], t23=T[11];
    const float t30=T[12], t31=T[13], t32=T[14], t33=T[15];
    const float fx  = calib_i[b*4+0], fy  = calib_i[b*4+1];
    const float cx  = calib_i[b*4+2], cy  = calib_i[b*4+3];
    const float li  = lam_i_p[b];
    const float fxj = calib_j[b*4+0], fyj = calib_j[b*4+1];
    const float cxj = calib_j[b*4+2], cyj = calib_j[b*4+3];
    const float lj  = lam_j_p[b];
    const float lj4 = 4.0f * lj;
    const float lj2 = 2.0f * lj;

    const float rfx = frcp(fx);
    const float rfy = frcp(fy);

    const float yn  = ((float)yrow - cy) * rfy;   // same for all 8 pixels of the row
    const float yn2 = yn * yn;
    const float xnb = ((float)x0 - cx) * rfx;     // xn at pixel 0; xn_i = fma(i, rfx, xnb)

    // Input: two float4 loads (8 consecutive inv_depth values)
    const f32x4* idp = reinterpret_cast<const f32x4*>(inv_depth + (size_t)b * HW + p0);
    float*       up  = out + (size_t)b * 3 * HW + p0;
    float*       mp  = out + (size_t)Bc * 3 * HW + (size_t)b * HW + p0;

#pragma unroll
    for (int g = 0; g < 2; ++g) {
        const f32x4 idv = idp[g];
        float u4[4], v4[4], rho4[4], m4[4];

#pragma unroll
        for (int i = 0; i < 4; ++i) {
            // undistort (division model, camera i)
            const float xn = fmaf((float)(g * 4 + i), rfx, xnb);
            const float r2 = fmaf(xn, xn, yn2);
            const float den = fmaf(li, r2, 1.0f);
            const bool valid_norm = den > EPSF;
            const float rden = frcp(valid_norm ? den : 1.0f);
            const float X0 = xn * rden;
            const float X1 = yn * rden;
            const float X3 = idv[i];
            // rigid 4x4 transform (X2 == 1)
            const float a  = ((t00 * X0 + t01 * X1) + t02) + t03 * X3;
            const float bb = ((t10 * X0 + t11 * X1) + t12) + t13 * X3;
            const float c  = ((t20 * X0 + t21 * X1) + t22) + t23 * X3;
            const float d  = ((t30 * X0 + t31 * X1) + t32) + t33 * X3;
            // perspective divide
            const bool mask_src = c > EPSF;
            const float rcz = frcp(mask_src ? c : 1.0f);
            const float xp = a * rcz;
            const float yp = bb * rcz;
            const float rho = d * rcz;
            // redistort (division model, camera j)
            const float ru2 = fmaf(xp, xp, yp * yp);
            const float disc = fmaf(-lj4, ru2, 1.0f);
            const bool valid_un = disc >= 0.0f;
            const float den2 = lj2 * ru2;
            const bool use_ratio = valid_un && (fabsf(den2) > EPSF);
            const float sqrt_disc = fsqrtf_(disc > 0.0f ? disc : 1.0f);
            const float ratio = use_ratio ? (1.0f - sqrt_disc) * frcp(den2) : 1.0f;
            const float xd = xp * ratio;
            const float yd = yp * ratio;
            // project (camera j)
            const float u = fmaf(fxj, xd, cxj);
            const float v = fmaf(fyj, yd, cyj);
            const bool inb = (u >= 0.0f) & (u <= (float)(Wc - 1)) &
                             (v >= 0.0f) & (v <= (float)(Hc - 1));
            const bool mask = mask_src & inb & valid_norm & valid_un;

            u4[i] = u; v4[i] = v; rho4[i] = rho;
            m4[i] = mask ? 1.0f : 0.0f;
        }

        // Streaming (non-temporal) float4 stores: 3 x_proj planes + mask plane
        const int o = g * 4;
        const f32x4 uv   = { u4[0], u4[1], u4[2], u4[3] };
        const f32x4 vv   = { v4[0], v4[1], v4[2], v4[3] };
        const f32x4 rhov = { rho4[0], rho4[1], rho4[2], rho4[3] };
        const f32x4 mv   = { m4[0], m4[1], m4[2], m4[3] };
        __builtin_nontemporal_store(uv,   reinterpret_cast<f32x4*>(up + o));
        __builtin_nontemporal_store(vv,   reinterpret_cast<f32x4*>(up + HW + o));
        __builtin_nontemporal_store(rhov, reinterpret_cast<f32x4*>(up + 2 * HW + o));
        __builtin_nontemporal_store(mv,   reinterpret_cast<f32x4*>(mp + o));
    }
}

extern "C" void kernel_launch(void* const* d_in, const int* in_sizes, int n_in,
                              void* d_out, int out_size, void* d_ws, size_t ws_size,
                              hipStream_t stream) {
    const float* inv_depth = (const float*)d_in[0];
    const float* transform = (const float*)d_in[1];
    const float* calib_i   = (const float*)d_in[2];
    const float* lam_i     = (const float*)d_in[3];
    const float* calib_j   = (const float*)d_in[4];
    const float* lam_j     = (const float*)d_in[5];
    // d_in[6] = non_rigid, always 0 for this problem (rigid einsum path)
    float* out = (float*)d_out;

    dim3 grid(BLOCKS_X, Bc);
    dim3 block(THREADS);
    transform_layer_kernel<<<grid, block, 0, stream>>>(
        inv_depth, transform, calib_i, lam_i, calib_j, lam_j, out);
}

// Round 5
// 28.475 us; speedup vs baseline: 2.6867x; 2.6867x over previous
//
#include <hip/hip_runtime.h>

// TransformLayer: per-pixel reprojection, B=8 H=768 W=1024, fp32.
// Memory-bound: ~12-25 MB HBM read + 100.7 MB write; output fits in 256MB LLC.
// R1: raw v_rcp/v_sqrt + FMA contraction (33->25.2 us).
// R3: nontemporal stores -> 76.5 us REGRESSION (2x HBM write amplification;
//     normal allocating stores let the LLC absorb the output). Reverted.
// R4: 8 px/thread + plain float4 stores.

#define EPSF 1e-06f

typedef float f32x4 __attribute__((ext_vector_type(4)));

constexpr int Bc = 8;
constexpr int Hc = 768;
constexpr int Wc = 1024;
constexpr int HW = Hc * Wc;          // 786432
constexpr int THREADS = 256;
constexpr int PIX_PER_THREAD = 8;    // 2 x float4 groups
constexpr int BLOCKS_X = HW / (THREADS * PIX_PER_THREAD); // 384

__device__ __forceinline__ float frcp(float x)   { return __builtin_amdgcn_rcpf(x); }
__device__ __forceinline__ float fsqrtf_(float x){ return __builtin_amdgcn_sqrtf(x); }

__global__ __launch_bounds__(THREADS)
void transform_layer_kernel(const float* __restrict__ inv_depth,
                            const float* __restrict__ transform,
                            const float* __restrict__ calib_i,
                            const float* __restrict__ lam_i_p,
                            const float* __restrict__ calib_j,
                            const float* __restrict__ lam_j_p,
                            float* __restrict__ out)
{
    const int b    = blockIdx.y;                          // batch (wave-uniform)
    const int g8   = blockIdx.x * THREADS + threadIdx.x;  // 8-pixel group index
    const int p0   = g8 * PIX_PER_THREAD;                 // first pixel in group
    const int yrow = p0 >> 10;                            // p0 / W
    const int x0   = p0 & (Wc - 1);                       // p0 % W (same row, W%8==0)

    // Per-batch params (uniform addresses -> scalar loads)
    const float* T = transform + b * 16;
    const float t00=T[0], t01=T[1], t02=T[2], t03=T[3];
    const float t10=T[4], t11=T[5], t12=T[6], t13=T[7];
    const float t20=T[8], t21=T[9], t22=T[10], t23=T[11];
    const float t30=T[12], t31=T[13], t32=T[14], t33=T[15];
    const float fx  = calib_i[b*4+0], fy  = calib_i[b*4+1];
    const float cx  = calib_i[b*4+2], cy  = calib_i[b*4+3];
    const float li  = lam_i_p[b];
    const float fxj = calib_j[b*4+0], fyj = calib_j[b*4+1];
    const float cxj = calib_j[b*4+2], cyj = calib_j[b*4+3];
    const float lj  = lam_j_p[b];
    const float lj4 = 4.0f * lj;
    const float lj2 = 2.0f * lj;

    const float rfx = frcp(fx);
    const float rfy = frcp(fy);

    const float yn  = ((float)yrow - cy) * rfy;   // same for all 8 pixels of the row
    const float yn2 = yn * yn;
    const float xnb = ((float)x0 - cx) * rfx;     // xn at pixel 0; xn_i = fma(i, rfx, xnb)

    // Input: two float4 loads (8 consecutive inv_depth values)
    const f32x4* idp = reinterpret_cast<const f32x4*>(inv_depth + (size_t)b * HW + p0);
    float*       up  = out + (size_t)b * 3 * HW + p0;
    float*       mp  = out + (size_t)Bc * 3 * HW + (size_t)b * HW + p0;

#pragma unroll
    for (int g = 0; g < 2; ++g) {
        const f32x4 idv = idp[g];
        float u4[4], v4[4], rho4[4], m4[4];

#pragma unroll
        for (int i = 0; i < 4; ++i) {
            // undistort (division model, camera i)
            const float xn = fmaf((float)(g * 4 + i), rfx, xnb);
            const float r2 = fmaf(xn, xn, yn2);
            const float den = fmaf(li, r2, 1.0f);
            const bool valid_norm = den > EPSF;
            const float rden = frcp(valid_norm ? den : 1.0f);
            const float X0 = xn * rden;
            const float X1 = yn * rden;
            const float X3 = idv[i];
            // rigid 4x4 transform (X2 == 1)
            const float a  = ((t00 * X0 + t01 * X1) + t02) + t03 * X3;
            const float bb = ((t10 * X0 + t11 * X1) + t12) + t13 * X3;
            const float c  = ((t20 * X0 + t21 * X1) + t22) + t23 * X3;
            const float d  = ((t30 * X0 + t31 * X1) + t32) + t33 * X3;
            // perspective divide
            const bool mask_src = c > EPSF;
            const float rcz = frcp(mask_src ? c : 1.0f);
            const float xp = a * rcz;
            const float yp = bb * rcz;
            const float rho = d * rcz;
            // redistort (division model, camera j)
            const float ru2 = fmaf(xp, xp, yp * yp);
            const float disc = fmaf(-lj4, ru2, 1.0f);
            const bool valid_un = disc >= 0.0f;
            const float den2 = lj2 * ru2;
            const bool use_ratio = valid_un && (fabsf(den2) > EPSF);
            const float sqrt_disc = fsqrtf_(disc > 0.0f ? disc : 1.0f);
            const float ratio = use_ratio ? (1.0f - sqrt_disc) * frcp(den2) : 1.0f;
            const float xd = xp * ratio;
            const float yd = yp * ratio;
            // project (camera j)
            const float u = fmaf(fxj, xd, cxj);
            const float v = fmaf(fyj, yd, cyj);
            const bool inb = (u >= 0.0f) & (u <= (float)(Wc - 1)) &
                             (v >= 0.0f) & (v <= (float)(Hc - 1));
            const bool mask = mask_src & inb & valid_norm & valid_un;

            u4[i] = u; v4[i] = v; rho4[i] = rho;
            m4[i] = mask ? 1.0f : 0.0f;
        }

        // Plain (allocating) float4 stores: 3 x_proj planes + mask plane.
        // Output fits in LLC -> allocating stores absorb at cache BW.
        const int o = g * 4;
        const f32x4 uv   = { u4[0], u4[1], u4[2], u4[3] };
        const f32x4 vv   = { v4[0], v4[1], v4[2], v4[3] };
        const f32x4 rhov = { rho4[0], rho4[1], rho4[2], rho4[3] };
        const f32x4 mv   = { m4[0], m4[1], m4[2], m4[3] };
        *reinterpret_cast<f32x4*>(up + o)          = uv;
        *reinterpret_cast<f32x4*>(up + HW + o)     = vv;
        *reinterpret_cast<f32x4*>(up + 2 * HW + o) = rhov;
        *reinterpret_cast<f32x4*>(mp + o)          = mv;
    }
}

extern "C" void kernel_launch(void* const* d_in, const int* in_sizes, int n_in,
                              void* d_out, int out_size, void* d_ws, size_t ws_size,
                              hipStream_t stream) {
    const float* inv_depth = (const float*)d_in[0];
    const float* transform = (const float*)d_in[1];
    const float* calib_i   = (const float*)d_in[2];
    const float* lam_i     = (const float*)d_in[3];
    const float* calib_j   = (const float*)d_in[4];
    const float* lam_j     = (const float*)d_in[5];
    // d_in[6] = non_rigid, always 0 for this problem (rigid einsum path)
    float* out = (float*)d_out;

    dim3 grid(BLOCKS_X, Bc);
    dim3 block(THREADS);
    transform_layer_kernel<<<grid, block, 0, stream>>>(
        inv_depth, transform, calib_i, lam_i, calib_j, lam_j, out);
}

// Round 6
// 24.904 us; speedup vs baseline: 3.0720x; 1.1434x over previous
//
#include <hip/hip_runtime.h>

// TransformLayer: per-pixel reprojection, B=8 H=768 W=1024, fp32.
// Memory-bound; output (100.7 MB) fits in 256MB LLC -> allocating stores.
// R1: raw v_rcp/v_sqrt + FMA contraction (33->25.2 us).
// R3: nontemporal stores -> 76.5 us REGRESSION (HBM write amplification). Reverted.
// R4: 8 px/thread with per-thread-consecutive pixels -> 28.5 us: lanes 32B apart
//     -> strided half-density wave access. Root cause found.
// R5: 8 px/thread, two groups each wave-coalesced (group stride THREADS*4).

#define EPSF 1e-06f

typedef float f32x4 __attribute__((ext_vector_type(4)));

constexpr int Bc = 8;
constexpr int Hc = 768;
constexpr int Wc = 1024;
constexpr int HW = Hc * Wc;          // 786432
constexpr int THREADS = 256;
constexpr int PIX_PER_THREAD = 8;    // 2 coalesced float4 groups
constexpr int BLOCK_PIX = THREADS * PIX_PER_THREAD;       // 2048
constexpr int GROUP_PIX = THREADS * 4;                    // 1024
constexpr int BLOCKS_X = HW / BLOCK_PIX;                  // 384

__device__ __forceinline__ float frcp(float x)   { return __builtin_amdgcn_rcpf(x); }
__device__ __forceinline__ float fsqrtf_(float x){ return __builtin_amdgcn_sqrtf(x); }

__global__ __launch_bounds__(THREADS)
void transform_layer_kernel(const float* __restrict__ inv_depth,
                            const float* __restrict__ transform,
                            const float* __restrict__ calib_i,
                            const float* __restrict__ lam_i_p,
                            const float* __restrict__ calib_j,
                            const float* __restrict__ lam_j_p,
                            float* __restrict__ out)
{
    const int b     = blockIdx.y;                         // batch (wave-uniform)
    const int pbase = blockIdx.x * BLOCK_PIX + threadIdx.x * 4;

    // Per-batch params (uniform addresses -> scalar loads)
    const float* T = transform + b * 16;
    const float t00=T[0], t01=T[1], t02=T[2], t03=T[3];
    const float t10=T[4], t11=T[5], t12=T[6], t13=T[7];
    const float t20=T[8], t21=T[9], t22=T[10], t23=T[11];
    const float t30=T[12], t31=T[13], t32=T[14], t33=T[15];
    const float fx  = calib_i[b*4+0], fy  = calib_i[b*4+1];
    const float cx  = calib_i[b*4+2], cy  = calib_i[b*4+3];
    const float li  = lam_i_p[b];
    const float fxj = calib_j[b*4+0], fyj = calib_j[b*4+1];
    const float cxj = calib_j[b*4+2], cyj = calib_j[b*4+3];
    const float lj  = lam_j_p[b];
    const float lj4 = 4.0f * lj;
    const float lj2 = 2.0f * lj;

    const float rfx = frcp(fx);
    const float rfy = frcp(fy);

    const float* idb = inv_depth + (size_t)b * HW;
    float*       ub  = out + (size_t)b * 3 * HW;
    float*       mb  = out + (size_t)Bc * 3 * HW + (size_t)b * HW;

#pragma unroll
    for (int g = 0; g < 2; ++g) {
        const int p0   = pbase + g * GROUP_PIX;           // first of 4 consecutive px
        const int yrow = p0 >> 10;                        // p0 / W
        const int x0   = p0 & (Wc - 1);                   // p0 % W (same row, W%4==0)

        const float yn  = ((float)yrow - cy) * rfy;
        const float yn2 = yn * yn;
        const float xnb = ((float)x0 - cx) * rfx;         // xn_i = fma(i, rfx, xnb)

        const f32x4 idv = *reinterpret_cast<const f32x4*>(idb + p0);
        float u4[4], v4[4], rho4[4], m4[4];

#pragma unroll
        for (int i = 0; i < 4; ++i) {
            // undistort (division model, camera i)
            const float xn = fmaf((float)i, rfx, xnb);
            const float r2 = fmaf(xn, xn, yn2);
            const float den = fmaf(li, r2, 1.0f);
            const bool valid_norm = den > EPSF;
            const float rden = frcp(valid_norm ? den : 1.0f);
            const float X0 = xn * rden;
            const float X1 = yn * rden;
            const float X3 = idv[i];
            // rigid 4x4 transform (X2 == 1)
            const float a  = ((t00 * X0 + t01 * X1) + t02) + t03 * X3;
            const float bb = ((t10 * X0 + t11 * X1) + t12) + t13 * X3;
            const float c  = ((t20 * X0 + t21 * X1) + t22) + t23 * X3;
            const float d  = ((t30 * X0 + t31 * X1) + t32) + t33 * X3;
            // perspective divide
            const bool mask_src = c > EPSF;
            const float rcz = frcp(mask_src ? c : 1.0f);
            const float xp = a * rcz;
            const float yp = bb * rcz;
            const float rho = d * rcz;
            // redistort (division model, camera j)
            const float ru2 = fmaf(xp, xp, yp * yp);
            const float disc = fmaf(-lj4, ru2, 1.0f);
            const bool valid_un = disc >= 0.0f;
            const float den2 = lj2 * ru2;
            const bool use_ratio = valid_un && (fabsf(den2) > EPSF);
            const float sqrt_disc = fsqrtf_(disc > 0.0f ? disc : 1.0f);
            const float ratio = use_ratio ? (1.0f - sqrt_disc) * frcp(den2) : 1.0f;
            const float xd = xp * ratio;
            const float yd = yp * ratio;
            // project (camera j)
            const float u = fmaf(fxj, xd, cxj);
            const float v = fmaf(fyj, yd, cyj);
            const bool inb = (u >= 0.0f) & (u <= (float)(Wc - 1)) &
                             (v >= 0.0f) & (v <= (float)(Hc - 1));
            const bool mask = mask_src & inb & valid_norm & valid_un;

            u4[i] = u; v4[i] = v; rho4[i] = rho;
            m4[i] = mask ? 1.0f : 0.0f;
        }

        // Wave-coalesced float4 stores: 3 x_proj planes + mask plane
        const f32x4 uv   = { u4[0], u4[1], u4[2], u4[3] };
        const f32x4 vv   = { v4[0], v4[1], v4[2], v4[3] };
        const f32x4 rhov = { rho4[0], rho4[1], rho4[2], rho4[3] };
        const f32x4 mv   = { m4[0], m4[1], m4[2], m4[3] };
        *reinterpret_cast<f32x4*>(ub + p0)          = uv;
        *reinterpret_cast<f32x4*>(ub + HW + p0)     = vv;
        *reinterpret_cast<f32x4*>(ub + 2 * HW + p0) = rhov;
        *reinterpret_cast<f32x4*>(mb + p0)          = mv;
    }
}

extern "C" void kernel_launch(void* const* d_in, const int* in_sizes, int n_in,
                              void* d_out, int out_size, void* d_ws, size_t ws_size,
                              hipStream_t stream) {
    const float* inv_depth = (const float*)d_in[0];
    const float* transform = (const float*)d_in[1];
    const float* calib_i   = (const float*)d_in[2];
    const float* lam_i     = (const float*)d_in[3];
    const float* calib_j   = (const float*)d_in[4];
    const float* lam_j     = (const float*)d_in[5];
    // d_in[6] = non_rigid, always 0 for this problem (rigid einsum path)
    float* out = (float*)d_out;

    dim3 grid(BLOCKS_X, Bc);
    dim3 block(THREADS);
    transform_layer_kernel<<<grid, block, 0, stream>>>(
        inv_depth, transform, calib_i, lam_i, calib_j, lam_j, out);
}

// Round 7
// 24.671 us; speedup vs baseline: 3.1010x; 1.0094x over previous
//
#include <hip/hip_runtime.h>

// TransformLayer: per-pixel reprojection, B=8 H=768 W=1024, fp32.
// Memory-bound; output (100.7 MB) fits in 256MB LLC -> allocating stores.
// R1: raw v_rcp/v_sqrt + FMA contraction (33->25.2 us).
// R3: nontemporal stores -> 76.5 us REGRESSION (HBM write amplification). Reverted.
// R5: 8 px/thread, two wave-coalesced float4 groups (24.9 us).
// R6: algebraic VALU cut: den-cancellation through the 4x4 transform
//     (a' = T·[xn,yn,den,X3*den], xp = a'/cz'), and stable ratio form
//     (1-sqrt(D))/den2 == 2/(1+sqrt(D)) with D scaled by cz'^2 so the
//     perspective divide cancels out of u,v: u = cxj + 2fxj*a'/(cz'+sqrt(disc')).
//     ~46->38 VALU ops, 4->3 trans per pixel. Fallback branches preserved
//     exactly via cz' = mask_src?c':den and denom = cz' + (valid_un?sq:cz').

#define EPSF 1e-06f

typedef float f32x4 __attribute__((ext_vector_type(4)));

constexpr int Bc = 8;
constexpr int Hc = 768;
constexpr int Wc = 1024;
constexpr int HW = Hc * Wc;          // 786432
constexpr int THREADS = 256;
constexpr int PIX_PER_THREAD = 8;    // 2 coalesced float4 groups
constexpr int BLOCK_PIX = THREADS * PIX_PER_THREAD;       // 2048
constexpr int GROUP_PIX = THREADS * 4;                    // 1024
constexpr int BLOCKS_X = HW / BLOCK_PIX;                  // 384

__device__ __forceinline__ float frcp(float x)   { return __builtin_amdgcn_rcpf(x); }
__device__ __forceinline__ float fsqrtf_(float x){ return __builtin_amdgcn_sqrtf(x); }

__global__ __launch_bounds__(THREADS)
void transform_layer_kernel(const float* __restrict__ inv_depth,
                            const float* __restrict__ transform,
                            const float* __restrict__ calib_i,
                            const float* __restrict__ lam_i_p,
                            const float* __restrict__ calib_j,
                            const float* __restrict__ lam_j_p,
                            float* __restrict__ out)
{
    const int b     = blockIdx.y;                         // batch (wave-uniform)
    const int pbase = blockIdx.x * BLOCK_PIX + threadIdx.x * 4;

    // Per-batch params (uniform addresses -> scalar loads)
    const float* T = transform + b * 16;
    const float t00=T[0], t01=T[1], t02=T[2], t03=T[3];
    const float t10=T[4], t11=T[5], t12=T[6], t13=T[7];
    const float t20=T[8], t21=T[9], t22=T[10], t23=T[11];
    const float t30=T[12], t31=T[13], t32=T[14], t33=T[15];
    const float fx  = calib_i[b*4+0], fy  = calib_i[b*4+1];
    const float cx  = calib_i[b*4+2], cy  = calib_i[b*4+3];
    const float li  = lam_i_p[b];
    const float fxj = calib_j[b*4+0], fyj = calib_j[b*4+1];
    const float cxj = calib_j[b*4+2], cyj = calib_j[b*4+3];
    const float lj  = lam_j_p[b];
    const float lj4 = 4.0f * lj;
    const float fxj2 = 2.0f * fxj;
    const float fyj2 = 2.0f * fyj;

    const float rfx = frcp(fx);
    const float rfy = frcp(fy);

    const float* idb = inv_depth + (size_t)b * HW;
    float*       ub  = out + (size_t)b * 3 * HW;
    float*       mb  = out + (size_t)Bc * 3 * HW + (size_t)b * HW;

#pragma unroll
    for (int g = 0; g < 2; ++g) {
        const int p0   = pbase + g * GROUP_PIX;           // first of 4 consecutive px
        const int yrow = p0 >> 10;                        // p0 / W
        const int x0   = p0 & (Wc - 1);                   // p0 % W (same row, W%4==0)

        const float yn  = ((float)yrow - cy) * rfy;
        const float xnb = ((float)x0 - cx) * rfx;         // xn_i = fma(i, rfx, xnb)
        const float den_y = fmaf(li, yn * yn, 1.0f);      // den = den_y + li*xn^2
        const float py_a = t01 * yn;                      // per-row partials
        const float py_b = t11 * yn;
        const float py_c = t21 * yn;
        const float py_d = t31 * yn;

        const f32x4 idv = *reinterpret_cast<const f32x4*>(idb + p0);
        float u4[4], v4[4], rho4[4], m4[4];

#pragma unroll
        for (int i = 0; i < 4; ++i) {
            const float xn  = fmaf((float)i, rfx, xnb);
            const float den = fmaf(li, xn * xn, den_y);
            const bool valid_norm = den > EPSF;
            const float X3 = idv[i];
            // homogeneous transform scaled by den: [xn, yn, den, X3*den]
            const float ap = fmaf(t00, xn, fmaf(fmaf(t03, X3, t02), den, py_a));
            const float bp = fmaf(t10, xn, fmaf(fmaf(t13, X3, t12), den, py_b));
            const float cp = fmaf(t20, xn, fmaf(fmaf(t23, X3, t22), den, py_c));
            const float dp = fmaf(t30, xn, fmaf(fmaf(t33, X3, t32), den, py_d));
            // perspective: xp = ap/cz (ref both branches: cz=c' valid, cz=den invalid)
            const bool  mask_src = cp > EPSF * den;
            const float cz  = mask_src ? cp : den;
            const float rcz = frcp(cz);
            const float rho = dp * rcz;
            // redistort, disc scaled by cz^2: disc' = cz^2 - 4*lj*(ap^2+bp^2)
            const float q     = fmaf(ap, ap, bp * bp);
            const float discp = fmaf(-lj4, q, cz * cz);
            const bool  valid_un = discp >= 0.0f;
            const float sq = fsqrtf_(fmaxf(discp, 0.0f));
            // ratio = 2/(1+sqrt(D)) (== (1-sqrt(D))/den2, stable);
            // invalid -> ratio=1 via denom = 2*cz
            const float denom = cz + (valid_un ? sq : cz);
            const float gg = frcp(denom);
            // u = cxj + 2*fxj*xp*ratio/... -> cz cancels: u = cxj + 2*fxj*ap/denom
            const float u = fmaf(fxj2, ap * gg, cxj);
            const float v = fmaf(fyj2, bp * gg, cyj);
            const bool inb = (u >= 0.0f) & (u <= (float)(Wc - 1)) &
                             (v >= 0.0f) & (v <= (float)(Hc - 1));
            const bool mask = mask_src & inb & valid_norm & valid_un;

            u4[i] = u; v4[i] = v; rho4[i] = rho;
            m4[i] = mask ? 1.0f : 0.0f;
        }

        // Wave-coalesced float4 stores: 3 x_proj planes + mask plane
        const f32x4 uv   = { u4[0], u4[1], u4[2], u4[3] };
        const f32x4 vv   = { v4[0], v4[1], v4[2], v4[3] };
        const f32x4 rhov = { rho4[0], rho4[1], rho4[2], rho4[3] };
        const f32x4 mv   = { m4[0], m4[1], m4[2], m4[3] };
        *reinterpret_cast<f32x4*>(ub + p0)          = uv;
        *reinterpret_cast<f32x4*>(ub + HW + p0)     = vv;
        *reinterpret_cast<f32x4*>(ub + 2 * HW + p0) = rhov;
        *reinterpret_cast<f32x4*>(mb + p0)          = mv;
    }
}

extern "C" void kernel_launch(void* const* d_in, const int* in_sizes, int n_in,
                              void* d_out, int out_size, void* d_ws, size_t ws_size,
                              hipStream_t stream) {
    const float* inv_depth = (const float*)d_in[0];
    const float* transform = (const float*)d_in[1];
    const float* calib_i   = (const float*)d_in[2];
    const float* lam_i     = (const float*)d_in[3];
    const float* calib_j   = (const float*)d_in[4];
    const float* lam_j     = (const float*)d_in[5];
    // d_in[6] = non_rigid, always 0 for this problem (rigid einsum path)
    float* out = (float*)d_out;

    dim3 grid(BLOCKS_X, Bc);
    dim3 block(THREADS);
    transform_layer_kernel<<<grid, block, 0, stream>>>(
        inv_depth, transform, calib_i, lam_i, calib_j, lam_j, out);
}